// Round 6
// baseline (184.126 us; speedup 1.0000x reference)
//
#include <hip/hip_runtime.h>
#include <hip/hip_bf16.h>
#include <math.h>

typedef __attribute__((ext_vector_type(8))) short bf16x8;
typedef __attribute__((ext_vector_type(4))) float f32x4;
typedef __attribute__((ext_vector_type(16))) float f32x16;

// async global->LDS, 16B per lane. LDS dest = wave-uniform base + lane*16.
static __device__ __forceinline__ void gld16(const void* g, void* l) {
    __builtin_amdgcn_global_load_lds(
        (const __attribute__((address_space(1))) unsigned int*)g,
        (__attribute__((address_space(3))) unsigned int*)l, 16, 0, 0);
}

// v_cvt_pk_bf16_f32: packs 2 f32 -> 2 bf16 in one u32 (lo = first arg).
static __device__ __forceinline__ unsigned cvtpk(float lo, float hi) {
    unsigned r;
    asm("v_cvt_pk_bf16_f32 %0, %1, %2" : "=v"(r) : "v"(lo), "v"(hi));
    return r;
}

// ---------------------------------------------------------------------------
// Kernel 1: merged PE+LayerNorm (blocks 0..4095) and W transpose+cast
// (blocks 4096..7167). Independent work, block-uniform branch.
// ---------------------------------------------------------------------------
__global__ __launch_bounds__(256) void peln_wt_kernel(
    const float* __restrict__ emb,
    const float* __restrict__ gamma,
    const float* __restrict__ beta,
    const float* __restrict__ Wq,
    const float* __restrict__ Wk,
    const float* __restrict__ Wv,
    __hip_bfloat16* __restrict__ x,
    __hip_bfloat16* __restrict__ Wt)
{
    const int tid = threadIdx.x;
    if (blockIdx.x < 4096) {
        const int row = blockIdx.x;
        const int t   = row & 1023;
        float4 e = ((const float4*)(emb + (size_t)row * 1024))[tid];
        float v[4] = {e.x, e.y, e.z, e.w};
        float s = 0.f, ss = 0.f;
        #pragma unroll
        for (int kk = 0; kk < 4; ++kk) {
            int c = tid * 4 + kk;
            float ang = (float)t * exp2f(-13.287712379549449f * (float)(c >> 1) * (1.0f / 512.0f));
            float pe  = (c & 1) ? __cosf(ang) : __sinf(ang);
            v[kk] += pe;
            s  += v[kk];
            ss += v[kk] * v[kk];
        }
        #pragma unroll
        for (int off = 1; off < 64; off <<= 1) {
            s  += __shfl_xor(s, off);
            ss += __shfl_xor(ss, off);
        }
        __shared__ float red_s[4], red_ss[4];
        int wave = tid >> 6, lane = tid & 63;
        if (lane == 0) { red_s[wave] = s; red_ss[wave] = ss; }
        __syncthreads();
        float S  = red_s[0] + red_s[1] + red_s[2] + red_s[3];
        float SS = red_ss[0] + red_ss[1] + red_ss[2] + red_ss[3];
        float mu   = S * (1.0f / 1024.0f);
        float var  = SS * (1.0f / 1024.0f) - mu * mu;
        float rstd = rsqrtf(var + 1e-5f);
        #pragma unroll
        for (int kk = 0; kk < 4; ++kk) {
            int c = tid * 4 + kk;
            float y = (v[kk] - mu) * rstd * gamma[c] + beta[c];
            x[(size_t)row * 1024 + c] = __float2bfloat16(y);
        }
    } else {
        __shared__ __hip_bfloat16 tile[32][33];
        int wid = blockIdx.x - 4096;         // 0..3071
        int zz  = wid >> 10;
        int rem = wid & 1023;
        int bx = rem & 31, by = rem >> 5;
        int tx = tid & 31, ty = tid >> 5;    // (32,8)
        const float* src = (zz == 0) ? Wq : (zz == 1) ? Wk : Wv;
        __hip_bfloat16* dst = Wt + (size_t)zz * 1024 * 1024;
        int x0 = bx * 32, y0 = by * 32;
        #pragma unroll
        for (int kk = 0; kk < 4; ++kk)
            tile[ty + 8 * kk][tx] =
                __float2bfloat16(src[(size_t)(y0 + ty + 8 * kk) * 1024 + x0 + tx]);
        __syncthreads();
        #pragma unroll
        for (int kk = 0; kk < 4; ++kk)
            dst[(size_t)(x0 + ty + 8 * kk) * 1024 + y0 + tx] = tile[tx][ty + 8 * kk];
    }
}

// ---------------------------------------------------------------------------
// Kernel 2: fused QKV GEMM. m97 loop (BK=64, XOR-swizzled LDS) with ROTATED
// pipeline: stage(n+1) issued after barrier-2, before MFMA(n) — the MFMA
// block shadows the staging latency. Coalesced LDS-bounce epilogue;
// t==2 (V) bounce transposed straight into vt.  (round-0 proven version;
// measured 29.5 us ~ 874 TF = m97-structure ceiling)
// ---------------------------------------------------------------------------
__global__ __launch_bounds__(256) void qkv_gemm(
    const __hip_bfloat16* __restrict__ X,    // [4096,1024] bf16
    const __hip_bfloat16* __restrict__ Wt,   // [3][1024][1024] bf16 N-major
    const float* __restrict__ bq,
    const float* __restrict__ bk,
    const float* __restrict__ bv,
    __hip_bfloat16* __restrict__ qkv,        // [2][4096][1024] bf16 (q,k)
    __hip_bfloat16* __restrict__ vt)         // [64][64][1024] bf16
{
    union SMem {
        struct { __hip_bfloat16 A[128 * 64]; __hip_bfloat16 B[128 * 64]; } s;
        __hip_bfloat16 C[128 * 132];         // epilogue bounce (pad 132)
    };
    __shared__ __align__(16) SMem sm;

    const int id   = blockIdx.x;             // 0..767
    const int xcd  = id & 7;
    const int rest = id >> 3;                // 0..95
    const int j    = rest % 3;
    const int mblk = rest / 3;               // 0..31
    const int m0   = mblk * 128;
    const int n0   = (xcd * 3 + j) * 128;    // 0..2944
    const int t    = n0 >> 10;
    const int nn0  = n0 & 1023;
    const __hip_bfloat16* W = Wt + (size_t)t * 1024 * 1024;

    const int tid  = threadIdx.x;
    const int wave = tid >> 6, lane = tid & 63;
    const int wm = wave & 1, wn = wave >> 1;
    const int lm = lane & 15, quad = lane >> 4;

    const int srow = lane >> 3;                        // 0..7
    const int skc  = ((lane & 7) ^ srow) * 8;          // element offset
    const int rbase = wave * 32;                       // rows this wave stages
    const __hip_bfloat16* gA = X + (size_t)(m0 + rbase + srow) * 1024 + skc;
    const __hip_bfloat16* gB = W + (size_t)(nn0 + rbase + srow) * 1024 + skc;
    __hip_bfloat16* lA = sm.s.A + rbase * 64;
    __hip_bfloat16* lB = sm.s.B + rbase * 64;

    f32x4 acc[4][4];
    #pragma unroll
    for (int i = 0; i < 4; ++i)
        #pragma unroll
        for (int jj = 0; jj < 4; ++jj)
            acc[i][jj] = (f32x4){0.f, 0.f, 0.f, 0.f};

    // prologue: stage tile 0
    #pragma unroll
    for (int n = 0; n < 4; ++n) {
        gld16(gA + (size_t)n * 8 * 1024, lA + n * 8 * 64);
        gld16(gB + (size_t)n * 8 * 1024, lB + n * 8 * 64);
    }

    for (int k0 = 0; k0 < 1024; k0 += 64) {
        __syncthreads();                     // drains stage(k0) (vmcnt in barrier)

        bf16x8 a[2][4], b[2][4];
        #pragma unroll
        for (int ks = 0; ks < 2; ++ks) {
            #pragma unroll
            for (int i = 0; i < 4; ++i) {
                int row = wm * 64 + i * 16 + lm;
                a[ks][i] = *(const bf16x8*)(sm.s.A + (size_t)row * 64
                                            + (((ks * 4 + quad) ^ (lm & 7)) * 8));
            }
            #pragma unroll
            for (int jj = 0; jj < 4; ++jj) {
                int row = wn * 64 + jj * 16 + lm;
                b[ks][jj] = *(const bf16x8*)(sm.s.B + (size_t)row * 64
                                             + (((ks * 4 + quad) ^ (lm & 7)) * 8));
            }
        }
        __syncthreads();                     // all LDS reads done

        if (k0 + 64 < 1024) {                // stage(k0+64) under MFMA shadow
            #pragma unroll
            for (int n = 0; n < 4; ++n) {
                gld16(gA + (size_t)n * 8 * 1024 + k0 + 64, lA + n * 8 * 64);
                gld16(gB + (size_t)n * 8 * 1024 + k0 + 64, lB + n * 8 * 64);
            }
        }

        #pragma unroll
        for (int ks = 0; ks < 2; ++ks)
            #pragma unroll
            for (int i = 0; i < 4; ++i)
                #pragma unroll
                for (int jj = 0; jj < 4; ++jj)
                    acc[i][jj] = __builtin_amdgcn_mfma_f32_16x16x32_bf16(a[ks][i], b[ks][jj], acc[i][jj], 0, 0, 0);
    }

    const float* bias = (t == 0) ? bq : (t == 1) ? bk : bv;
    if (t < 2) {
        #pragma unroll
        for (int jj = 0; jj < 4; ++jj) {
            int col = wn * 64 + jj * 16 + lm;
            float bb = bias[nn0 + col];
            #pragma unroll
            for (int i = 0; i < 4; ++i)
                #pragma unroll
                for (int r = 0; r < 4; ++r) {
                    int row = wm * 64 + i * 16 + quad * 4 + r;
                    sm.C[(size_t)row * 132 + col] = __float2bfloat16(acc[i][jj][r] + bb);
                }
        }
        __syncthreads();
        __hip_bfloat16* out = qkv + (size_t)t * 4096 * 1024;
        #pragma unroll
        for (int c = 0; c < 8; ++c) {
            int g = tid + 256 * c;               // 0..2047 chunks of 16B
            int row = g >> 4;
            int colc = (g & 15) * 8;
            bf16x8 vch = *(const bf16x8*)&sm.C[(size_t)row * 132 + colc];
            *(bf16x8*)(out + (size_t)(m0 + row) * 1024 + nn0 + colc) = vch;
        }
    } else {
        #pragma unroll
        for (int jj = 0; jj < 4; ++jj) {
            int col = wn * 64 + jj * 16 + lm;
            float bb = bias[nn0 + col];
            #pragma unroll
            for (int i = 0; i < 4; ++i)
                #pragma unroll
                for (int r = 0; r < 4; ++r) {
                    int row = wm * 64 + i * 16 + quad * 4 + r;
                    sm.C[(size_t)col * 132 + row] = __float2bfloat16(acc[i][jj][r] + bb);
                }
        }
        __syncthreads();
        const int bbase = (m0 >> 10) * 16 + (nn0 >> 6);
        const int mloc  = m0 & 1023;
        #pragma unroll
        for (int c = 0; c < 8; ++c) {
            int g = tid + 256 * c;               // 0..2047
            int col = g >> 4;                    // 0..127
            int rch = (g & 15) * 8;              // token chunk
            bf16x8 vch = *(const bf16x8*)&sm.C[(size_t)col * 132 + rch];
            int bh = bbase + (col >> 6);
            int d  = col & 63;
            *(bf16x8*)(vt + ((size_t)bh * 64 + d) * 1024 + mloc + rch) = vch;
        }
    }
}

// ---------------------------------------------------------------------------
// Kernel 3: flash attention v11 — DIRECT-L2, zero LDS, zero barriers.
// K/V per (b,h) = 256 KB, per-XCD working set 2 MB -> fully L2-resident
// (bh mapping keeps 8 bh per XCD). LDS staging of L2-fit data was pure
// convoy overhead (per-tile __syncthreads drains vmcnt(0) at 2 waves/SIMD).
// Fragments are read straight from global with the SAME values as the old
// swizzled-LDS path (stage swizzle was an involution) -> bitwise-identical
// results. 32x32x16 MFMA, in-register P via cvt_pk + permlane32_swap,
// max-free softmax.
// ---------------------------------------------------------------------------
__global__ __launch_bounds__(256, 2) void attn_kernel(
    const __hip_bfloat16* __restrict__ q,    // [4096,1024]
    const __hip_bfloat16* __restrict__ k,    // [4096,1024]
    const __hip_bfloat16* __restrict__ vt,   // [64][64][1024]
    float* __restrict__ out)                 // [4096,1024] f32
{
    const int id   = blockIdx.x;             // 0..511
    const int bh   = (id & 7) * 8 + ((id >> 3) & 7);  // XCD-local K/V
    const int qblk = id >> 6;                // 0..7
    const int b = bh >> 4, h = bh & 15;
    const int wave = threadIdx.x >> 6, lane = threadIdx.x & 63;
    const int l31 = lane & 31, hi5 = lane >> 5;
    const int qbase = qblk * 128 + wave * 32;
    const float CEXP = 0.18033688011112042f; // (1/8) * log2(e)

    // Q fragments: B-operand of 32x32x16, col=q=l31, k(d) = 8*hi5 + e per slab
    bf16x8 bq32[4];
    #pragma unroll
    for (int slab = 0; slab < 4; ++slab)
        bq32[slab] = *(const bf16x8*)(q + (size_t)(b * 1024 + qbase + l31) * 1024
                                        + h * 64 + (slab * 2 + hi5) * 8);

    const __hip_bfloat16* kg = k + (size_t)(b * 1024) * 1024 + h * 64;   // [key][d]
    const __hip_bfloat16* vg = vt + (size_t)bh * 64 * 1024;              // [d][key]

    f32x16 OT[2];          // O^T accumulators: [dt], col=q, row=d pattern
    #pragma unroll
    for (int dt = 0; dt < 2; ++dt)
        #pragma unroll
        for (int r = 0; r < 16; ++r)
            OT[dt][r] = 0.f;
    float li = 0.f;

    for (int kc = 0; kc < 1024; kc += 64) {
        // ---- QK^T: S^T[64 keys][32 q], 2 key-subtiles x 4 d-slabs ----
        f32x16 ST[2];
        #pragma unroll
        for (int kt = 0; kt < 2; ++kt) {
            #pragma unroll
            for (int r = 0; r < 16; ++r) ST[kt][r] = 0.f;
            #pragma unroll
            for (int slab = 0; slab < 4; ++slab) {
                bf16x8 ak = *(const bf16x8*)(kg
                    + (size_t)(kc + kt * 32 + l31) * 1024
                    + (slab * 2 + hi5) * 8);
                ST[kt] = __builtin_amdgcn_mfma_f32_32x32x16_bf16(ak, bq32[slab], ST[kt], 0, 0, 0);
            }
        }

        // ---- softmax (max-free) + pack P^T into PV B-operand words ----
        unsigned pw[4][4];               // [ks][word]
        #pragma unroll
        for (int kt = 0; kt < 2; ++kt) {
            float pv[16];
            #pragma unroll
            for (int r = 0; r < 16; ++r) {
                pv[r] = __builtin_amdgcn_exp2f(ST[kt][r] * CEXP);
                li += pv[r];
            }
            #pragma unroll
            for (int s = 0; s < 2; ++s) {
                unsigned P0 = cvtpk(pv[8 * s + 0], pv[8 * s + 1]);
                unsigned P1 = cvtpk(pv[8 * s + 2], pv[8 * s + 3]);
                unsigned P2 = cvtpk(pv[8 * s + 4], pv[8 * s + 5]);
                unsigned P3 = cvtpk(pv[8 * s + 6], pv[8 * s + 7]);
                asm("v_permlane32_swap_b32 %0, %1" : "+v"(P0), "+v"(P2));
                asm("v_permlane32_swap_b32 %0, %1" : "+v"(P1), "+v"(P3));
                int ks = kt * 2 + s;
                pw[ks][0] = P0; pw[ks][1] = P1; pw[ks][2] = P2; pw[ks][3] = P3;
            }
        }

        // ---- PV: O^T[64 d][32 q] += V^T · P^T ----
        #pragma unroll
        for (int dt = 0; dt < 2; ++dt)
            #pragma unroll
            for (int ks = 0; ks < 4; ++ks) {
                bf16x8 av = *(const bf16x8*)(vg
                    + (size_t)(dt * 32 + l31) * 1024
                    + kc + (ks * 2 + hi5) * 8);
                bf16x8 pf;
                __builtin_memcpy(&pf, pw[ks], 16);
                OT[dt] = __builtin_amdgcn_mfma_f32_32x32x16_bf16(av, pf, OT[dt], 0, 0, 0);
            }
    }

    li += __shfl_xor(li, 32);
    float inv = 1.0f / li;
    const int qrow = qbase + l31;

    #pragma unroll
    for (int dt = 0; dt < 2; ++dt)
        #pragma unroll
        for (int g = 0; g < 4; ++g) {
            float4 o4 = {OT[dt][4 * g + 0] * inv, OT[dt][4 * g + 1] * inv,
                         OT[dt][4 * g + 2] * inv, OT[dt][4 * g + 3] * inv};
            *(float4*)(out + (size_t)(b * 1024 + qrow) * 1024
                       + h * 64 + dt * 32 + 8 * g + 4 * hi5) = o4;
        }
}

// ---------------------------------------------------------------------------
extern "C" void kernel_launch(void* const* d_in, const int* in_sizes, int n_in,
                              void* d_out, int out_size, void* d_ws, size_t ws_size,
                              hipStream_t stream)
{
    const float* emb   = (const float*)d_in[0];
    const float* gamma = (const float*)d_in[1];
    const float* beta  = (const float*)d_in[2];
    const float* Wq    = (const float*)d_in[3];
    const float* bq    = (const float*)d_in[4];
    const float* Wk    = (const float*)d_in[5];
    const float* bk    = (const float*)d_in[6];
    const float* Wv    = (const float*)d_in[7];
    const float* bv    = (const float*)d_in[8];
    float* out = (float*)d_out;

    __hip_bfloat16* ws  = (__hip_bfloat16*)d_ws;
    __hip_bfloat16* x   = ws;                            //  4M elems bf16
    __hip_bfloat16* Wt  = x   + (size_t)4096 * 1024;     //  3M elems
    __hip_bfloat16* qkv = Wt  + (size_t)3 * 1024 * 1024; //  8M elems (q,k)
    __hip_bfloat16* vt  = qkv + (size_t)2 * 4096 * 1024; //  4M elems (38MB)

    peln_wt_kernel<<<4096 + 3072, 256, 0, stream>>>(emb, gamma, beta, Wq, Wk, Wv, x, Wt);
    qkv_gemm<<<768, 256, 0, stream>>>(x, Wt, bq, bk, bv, qkv, vt);
    attn_kernel<<<512, 256, 0, stream>>>(qkv, qkv + (size_t)4096 * 1024, vt, out);
}

// Round 8
// 151.696 us; speedup vs baseline: 1.2138x; 1.2138x over previous
//
#include <hip/hip_runtime.h>
#include <hip/hip_bf16.h>
#include <math.h>

typedef __attribute__((ext_vector_type(8))) short bf16x8;
typedef __attribute__((ext_vector_type(4))) short bf16x4;
typedef __attribute__((ext_vector_type(4))) float f32x4;

// async global->LDS, 16B per lane. LDS dest = wave-uniform base + lane*16.
static __device__ __forceinline__ void gld16(const void* g, void* l) {
    __builtin_amdgcn_global_load_lds(
        (const __attribute__((address_space(1))) unsigned int*)g,
        (__attribute__((address_space(3))) unsigned int*)l, 16, 0, 0);
}

static __device__ __forceinline__ short f2bf_s(float f) {
    __hip_bfloat16 h = __float2bfloat16(f);
    short s;
    __builtin_memcpy(&s, &h, 2);
    return s;
}

// ---------------------------------------------------------------------------
// Kernel 1: merged PE+LayerNorm (blocks 0..4095) and W transpose+cast
// (blocks 4096..7167). Independent work, block-uniform branch.
// ---------------------------------------------------------------------------
__global__ __launch_bounds__(256) void peln_wt_kernel(
    const float* __restrict__ emb,
    const float* __restrict__ gamma,
    const float* __restrict__ beta,
    const float* __restrict__ Wq,
    const float* __restrict__ Wk,
    const float* __restrict__ Wv,
    __hip_bfloat16* __restrict__ x,
    __hip_bfloat16* __restrict__ Wt)
{
    const int tid = threadIdx.x;
    if (blockIdx.x < 4096) {
        const int row = blockIdx.x;
        const int t   = row & 1023;
        float4 e = ((const float4*)(emb + (size_t)row * 1024))[tid];
        float v[4] = {e.x, e.y, e.z, e.w};
        float s = 0.f, ss = 0.f;
        #pragma unroll
        for (int kk = 0; kk < 4; ++kk) {
            int c = tid * 4 + kk;
            float ang = (float)t * exp2f(-13.287712379549449f * (float)(c >> 1) * (1.0f / 512.0f));
            float pe  = (c & 1) ? __cosf(ang) : __sinf(ang);
            v[kk] += pe;
            s  += v[kk];
            ss += v[kk] * v[kk];
        }
        #pragma unroll
        for (int off = 1; off < 64; off <<= 1) {
            s  += __shfl_xor(s, off);
            ss += __shfl_xor(ss, off);
        }
        __shared__ float red_s[4], red_ss[4];
        int wave = tid >> 6, lane = tid & 63;
        if (lane == 0) { red_s[wave] = s; red_ss[wave] = ss; }
        __syncthreads();
        float S  = red_s[0] + red_s[1] + red_s[2] + red_s[3];
        float SS = red_ss[0] + red_ss[1] + red_ss[2] + red_ss[3];
        float mu   = S * (1.0f / 1024.0f);
        float var  = SS * (1.0f / 1024.0f) - mu * mu;
        float rstd = rsqrtf(var + 1e-5f);
        #pragma unroll
        for (int kk = 0; kk < 4; ++kk) {
            int c = tid * 4 + kk;
            float y = (v[kk] - mu) * rstd * gamma[c] + beta[c];
            x[(size_t)row * 1024 + c] = __float2bfloat16(y);
        }
    } else {
        __shared__ __hip_bfloat16 tile[32][33];
        int wid = blockIdx.x - 4096;         // 0..3071
        int zz  = wid >> 10;
        int rem = wid & 1023;
        int bx = rem & 31, by = rem >> 5;
        int tx = tid & 31, ty = tid >> 5;    // (32,8)
        const float* src = (zz == 0) ? Wq : (zz == 1) ? Wk : Wv;
        __hip_bfloat16* dst = Wt + (size_t)zz * 1024 * 1024;
        int x0 = bx * 32, y0 = by * 32;
        #pragma unroll
        for (int kk = 0; kk < 4; ++kk)
            tile[ty + 8 * kk][tx] =
                __float2bfloat16(src[(size_t)(y0 + ty + 8 * kk) * 1024 + x0 + tx]);
        __syncthreads();
        #pragma unroll
        for (int kk = 0; kk < 4; ++kk)
            dst[(size_t)(x0 + ty + 8 * kk) * 1024 + y0 + tx] = tile[tx][ty + 8 * kk];
    }
}

// ---------------------------------------------------------------------------
// Kernel 2: fused QKV GEMM. m97 loop (BK=64, XOR-swizzled LDS) with ROTATED
// pipeline. Measured 29.5 us ~ 874 TF = m97-structure ceiling. Unchanged.
// ---------------------------------------------------------------------------
__global__ __launch_bounds__(256) void qkv_gemm(
    const __hip_bfloat16* __restrict__ X,    // [4096,1024] bf16
    const __hip_bfloat16* __restrict__ Wt,   // [3][1024][1024] bf16 N-major
    const float* __restrict__ bq,
    const float* __restrict__ bk,
    const float* __restrict__ bv,
    __hip_bfloat16* __restrict__ qkv,        // [2][4096][1024] bf16 (q,k)
    __hip_bfloat16* __restrict__ vt)         // [64][64][1024] bf16
{
    union SMem {
        struct { __hip_bfloat16 A[128 * 64]; __hip_bfloat16 B[128 * 64]; } s;
        __hip_bfloat16 C[128 * 132];         // epilogue bounce (pad 132)
    };
    __shared__ __align__(16) SMem sm;

    const int id   = blockIdx.x;             // 0..767
    const int xcd  = id & 7;
    const int rest = id >> 3;                // 0..95
    const int j    = rest % 3;
    const int mblk = rest / 3;               // 0..31
    const int m0   = mblk * 128;
    const int n0   = (xcd * 3 + j) * 128;    // 0..2944
    const int t    = n0 >> 10;
    const int nn0  = n0 & 1023;
    const __hip_bfloat16* W = Wt + (size_t)t * 1024 * 1024;

    const int tid  = threadIdx.x;
    const int wave = tid >> 6, lane = tid & 63;
    const int wm = wave & 1, wn = wave >> 1;
    const int lm = lane & 15, quad = lane >> 4;

    const int srow = lane >> 3;                        // 0..7
    const int skc  = ((lane & 7) ^ srow) * 8;          // element offset
    const int rbase = wave * 32;                       // rows this wave stages
    const __hip_bfloat16* gA = X + (size_t)(m0 + rbase + srow) * 1024 + skc;
    const __hip_bfloat16* gB = W + (size_t)(nn0 + rbase + srow) * 1024 + skc;
    __hip_bfloat16* lA = sm.s.A + rbase * 64;
    __hip_bfloat16* lB = sm.s.B + rbase * 64;

    f32x4 acc[4][4];
    #pragma unroll
    for (int i = 0; i < 4; ++i)
        #pragma unroll
        for (int jj = 0; jj < 4; ++jj)
            acc[i][jj] = (f32x4){0.f, 0.f, 0.f, 0.f};

    // prologue: stage tile 0
    #pragma unroll
    for (int n = 0; n < 4; ++n) {
        gld16(gA + (size_t)n * 8 * 1024, lA + n * 8 * 64);
        gld16(gB + (size_t)n * 8 * 1024, lB + n * 8 * 64);
    }

    for (int k0 = 0; k0 < 1024; k0 += 64) {
        __syncthreads();                     // drains stage(k0) (vmcnt in barrier)

        bf16x8 a[2][4], b[2][4];
        #pragma unroll
        for (int ks = 0; ks < 2; ++ks) {
            #pragma unroll
            for (int i = 0; i < 4; ++i) {
                int row = wm * 64 + i * 16 + lm;
                a[ks][i] = *(const bf16x8*)(sm.s.A + (size_t)row * 64
                                            + (((ks * 4 + quad) ^ (lm & 7)) * 8));
            }
            #pragma unroll
            for (int jj = 0; jj < 4; ++jj) {
                int row = wn * 64 + jj * 16 + lm;
                b[ks][jj] = *(const bf16x8*)(sm.s.B + (size_t)row * 64
                                             + (((ks * 4 + quad) ^ (lm & 7)) * 8));
            }
        }
        __syncthreads();                     // all LDS reads done

        if (k0 + 64 < 1024) {                // stage(k0+64) under MFMA shadow
            #pragma unroll
            for (int n = 0; n < 4; ++n) {
                gld16(gA + (size_t)n * 8 * 1024 + k0 + 64, lA + n * 8 * 64);
                gld16(gB + (size_t)n * 8 * 1024 + k0 + 64, lB + n * 8 * 64);
            }
        }

        #pragma unroll
        for (int ks = 0; ks < 2; ++ks)
            #pragma unroll
            for (int i = 0; i < 4; ++i)
                #pragma unroll
                for (int jj = 0; jj < 4; ++jj)
                    acc[i][jj] = __builtin_amdgcn_mfma_f32_16x16x32_bf16(a[ks][i], b[ks][jj], acc[i][jj], 0, 0, 0);
    }

    const float* bias = (t == 0) ? bq : (t == 1) ? bk : bv;
    if (t < 2) {
        #pragma unroll
        for (int jj = 0; jj < 4; ++jj) {
            int col = wn * 64 + jj * 16 + lm;
            float bb = bias[nn0 + col];
            #pragma unroll
            for (int i = 0; i < 4; ++i)
                #pragma unroll
                for (int r = 0; r < 4; ++r) {
                    int row = wm * 64 + i * 16 + quad * 4 + r;
                    sm.C[(size_t)row * 132 + col] = __float2bfloat16(acc[i][jj][r] + bb);
                }
        }
        __syncthreads();
        __hip_bfloat16* out = qkv + (size_t)t * 4096 * 1024;
        #pragma unroll
        for (int c = 0; c < 8; ++c) {
            int g = tid + 256 * c;               // 0..2047 chunks of 16B
            int row = g >> 4;
            int colc = (g & 15) * 8;
            bf16x8 vch = *(const bf16x8*)&sm.C[(size_t)row * 132 + colc];
            *(bf16x8*)(out + (size_t)(m0 + row) * 1024 + nn0 + colc) = vch;
        }
    } else {
        #pragma unroll
        for (int jj = 0; jj < 4; ++jj) {
            int col = wn * 64 + jj * 16 + lm;
            float bb = bias[nn0 + col];
            #pragma unroll
            for (int i = 0; i < 4; ++i)
                #pragma unroll
                for (int r = 0; r < 4; ++r) {
                    int row = wm * 64 + i * 16 + quad * 4 + r;
                    sm.C[(size_t)col * 132 + row] = __float2bfloat16(acc[i][jj][r] + bb);
                }
        }
        __syncthreads();
        const int bbase = (m0 >> 10) * 16 + (nn0 >> 6);
        const int mloc  = m0 & 1023;
        #pragma unroll
        for (int c = 0; c < 8; ++c) {
            int g = tid + 256 * c;               // 0..2047
            int col = g >> 4;                    // 0..127
            int rch = (g & 15) * 8;              // token chunk
            bf16x8 vch = *(const bf16x8*)&sm.C[(size_t)col * 132 + rch];
            int bh = bbase + (col >> 6);
            int d  = col & 63;
            *(bf16x8*)(vt + ((size_t)bh * 64 + d) * 1024 + mloc + rch) = vch;
        }
    }
}

// ---------------------------------------------------------------------------
// Kernel 3: flash attention v12 — OCCUPANCY FIX. 16 q per wave (was 32),
// 64 q per block, 1024 blocks -> 4 waves/SIMD, 4 blocks/CU (LDS = 40 KB
// exactly). v11 counters proved latency-bound (MfmaUtil 9%, VALU 14%, all
// pipes idle); every prior variant was stuck at 2 waves/SIMD by the
// 32-q-per-wave decomposition. Fragment math identical to v8/v9
// (HW-verified): 16x16x32 MFMA, XOR-swizzled K/V staging, swizzled
// wave-private ldsPT for P^T, max-free softmax, dbuf K/V, 64-key tiles.
// (Resubmitted unchanged — round-7 failure was container infra, and a
// hang-audit found no divergent barrier / race / resource overrun.)
// ---------------------------------------------------------------------------
__global__ __launch_bounds__(256, 4) void attn_kernel(
    const __hip_bfloat16* __restrict__ q,    // [4096,1024]
    const __hip_bfloat16* __restrict__ k,    // [4096,1024]
    const __hip_bfloat16* __restrict__ vt,   // [64][64][1024]
    float* __restrict__ out)                 // [4096,1024] f32
{
    __shared__ __align__(16) __hip_bfloat16 Kbuf[2][64 * 64];  // 16 KB
    __shared__ __align__(16) __hip_bfloat16 Vbuf[2][64 * 64];  // 16 KB
    __shared__ short ldsPT[4][16 * 64];                        //  8 KB
    const int id   = blockIdx.x;             // 0..1023
    const int bh   = (id & 7) * 8 + ((id >> 3) & 7);  // XCD-local K/V
    const int qblk = id >> 6;                // 0..15
    const int b = bh >> 4, h = bh & 15;
    const int wave = threadIdx.x >> 6, lane = threadIdx.x & 63;
    const int lm = lane & 15, quad = lane >> 4;
    const int qbase = qblk * 64 + wave * 16;
    const float CEXP = 0.18033688011112042f; // (1/8) * log2(e)

    // Q fragment: B-operand, col=q=lm, k(d) = ks*32 + quad*8 + e
    bf16x8 bqf[2];
    #pragma unroll
    for (int ks = 0; ks < 2; ++ks)
        bqf[ks] = *(const bf16x8*)(q + (size_t)(b * 1024 + qbase + lm) * 1024
                                     + h * 64 + ks * 32 + quad * 8);

    const __hip_bfloat16* kg = k + (size_t)(b * 1024) * 1024 + h * 64;   // [key][d]
    const __hip_bfloat16* vg = vt + (size_t)bh * 64 * 1024;              // [d][key]
    const int srow = lane >> 3;                  // 0..7
    const int skc  = ((lane & 7) ^ srow) * 8;    // swizzled source chunk

    f32x4 OT[4];           // O^T: [dt] rows=d (quad*4+r), col=q=lm
    #pragma unroll
    for (int dt = 0; dt < 4; ++dt)
        OT[dt] = (f32x4){0.f, 0.f, 0.f, 0.f};
    float li = 0.f;

    // stage K [64 keys][64 d] and V [64 d][64 keys] for key-window kt0
    auto stageKV = [&](int buf, int kt0) {
        #pragma unroll
        for (int n = 0; n < 2; ++n) {
            int r0 = wave * 16 + n * 8;
            gld16(kg + (size_t)(kt0 + r0 + srow) * 1024 + skc, Kbuf[buf] + r0 * 64);
        }
        #pragma unroll
        for (int n = 0; n < 2; ++n) {
            int d0 = wave * 16 + n * 8;
            gld16(vg + (size_t)(d0 + srow) * 1024 + kt0 + skc, Vbuf[buf] + d0 * 64);
        }
    };

    stageKV(0, 0);                           // prologue

    for (int tt = 0; tt < 16; ++tt) {
        __syncthreads();                     // stage(tt) landed; buf^1 readers done
        if (tt + 1 < 16) stageKV((tt + 1) & 1, (tt + 1) * 64);

        const __hip_bfloat16* Kb = Kbuf[tt & 1];
        const __hip_bfloat16* Vb = Vbuf[tt & 1];

        // ---- QK^T: S^T[64 keys][16 q] as 4 kt-tiles ----
        f32x4 ST[4];
        #pragma unroll
        for (int kt = 0; kt < 4; ++kt) {
            ST[kt] = (f32x4){0.f, 0.f, 0.f, 0.f};
            #pragma unroll
            for (int ks = 0; ks < 2; ++ks) {
                bf16x8 ak = *(const bf16x8*)(Kb + (size_t)(kt * 16 + lm) * 64
                                             + (((ks * 4 + quad) ^ (lm & 7)) * 8));
                ST[kt] = __builtin_amdgcn_mfma_f32_16x16x32_bf16(ak, bqf[ks], ST[kt], 0, 0, 0);
            }
        }

        // ---- softmax (max-free) + P^T into swizzled wave-private LDS ----
        #pragma unroll
        for (int kt = 0; kt < 4; ++kt) {
            bf16x4 pk;
            #pragma unroll
            for (int r = 0; r < 4; ++r) {
                float p = __builtin_amdgcn_exp2f(ST[kt][r] * CEXP);
                li += p;
                pk[r] = f2bf_s(p);
            }
            int u = kt * 2 + (quad >> 1);    // 16B-chunk index of key kt*16+quad*4
            *(bf16x4*)&ldsPT[wave][lm * 64 + ((u ^ (lm & 7)) << 3) + (quad & 1) * 4] = pk;
        }

        bf16x8 bp[2];
        #pragma unroll
        for (int ks = 0; ks < 2; ++ks)
            bp[ks] = *(const bf16x8*)&ldsPT[wave][lm * 64
                      + (((ks * 4 + quad) ^ (lm & 7)) << 3)];

        // ---- PV: O^T[64 d][16 q] += V^T · P^T ----
        #pragma unroll
        for (int dt = 0; dt < 4; ++dt)
            #pragma unroll
            for (int ks = 0; ks < 2; ++ks) {
                bf16x8 av = *(const bf16x8*)(Vb + (size_t)(dt * 16 + lm) * 64
                                             + (((ks * 4 + quad) ^ (lm & 7)) * 8));
                OT[dt] = __builtin_amdgcn_mfma_f32_16x16x32_bf16(av, bp[ks], OT[dt], 0, 0, 0);
            }
    }

    li += __shfl_xor(li, 16);
    li += __shfl_xor(li, 32);
    float inv = 1.0f / li;
    const int qrow = qbase + lm;

    #pragma unroll
    for (int dt = 0; dt < 4; ++dt) {
        float4 o4 = {OT[dt][0] * inv, OT[dt][1] * inv,
                     OT[dt][2] * inv, OT[dt][3] * inv};
        *(float4*)(out + (size_t)(b * 1024 + qrow) * 1024
                   + h * 64 + dt * 16 + quad * 4) = o4;
    }
}

// ---------------------------------------------------------------------------
extern "C" void kernel_launch(void* const* d_in, const int* in_sizes, int n_in,
                              void* d_out, int out_size, void* d_ws, size_t ws_size,
                              hipStream_t stream)
{
    const float* emb   = (const float*)d_in[0];
    const float* gamma = (const float*)d_in[1];
    const float* beta  = (const float*)d_in[2];
    const float* Wq    = (const float*)d_in[3];
    const float* bq    = (const float*)d_in[4];
    const float* Wk    = (const float*)d_in[5];
    const float* bk    = (const float*)d_in[6];
    const float* Wv    = (const float*)d_in[7];
    const float* bv    = (const float*)d_in[8];
    float* out = (float*)d_out;

    __hip_bfloat16* ws  = (__hip_bfloat16*)d_ws;
    __hip_bfloat16* x   = ws;                            //  4M elems bf16
    __hip_bfloat16* Wt  = x   + (size_t)4096 * 1024;     //  3M elems
    __hip_bfloat16* qkv = Wt  + (size_t)3 * 1024 * 1024; //  8M elems (q,k)
    __hip_bfloat16* vt  = qkv + (size_t)2 * 4096 * 1024; //  4M elems (38MB)

    peln_wt_kernel<<<4096 + 3072, 256, 0, stream>>>(emb, gamma, beta, Wq, Wk, Wv, x, Wt);
    qkv_gemm<<<768, 256, 0, stream>>>(x, Wt, bq, bk, bv, qkv, vt);
    attn_kernel<<<1024, 256, 0, stream>>>(qkv, qkv + (size_t)4096 * 1024, vt, out);
}

// Round 9
// 148.541 us; speedup vs baseline: 1.2396x; 1.0212x over previous
//
#include <hip/hip_runtime.h>
#include <hip/hip_bf16.h>
#include <math.h>

typedef __attribute__((ext_vector_type(8))) short bf16x8;
typedef __attribute__((ext_vector_type(4))) float f32x4;
typedef __attribute__((ext_vector_type(16))) float f32x16;

// async global->LDS, 16B per lane. LDS dest = wave-uniform base + lane*16.
static __device__ __forceinline__ void gld16(const void* g, void* l) {
    __builtin_amdgcn_global_load_lds(
        (const __attribute__((address_space(1))) unsigned int*)g,
        (__attribute__((address_space(3))) unsigned int*)l, 16, 0, 0);
}

// v_cvt_pk_bf16_f32: packs 2 f32 -> 2 bf16 in one u32 (lo = first arg).
static __device__ __forceinline__ unsigned cvtpk(float lo, float hi) {
    unsigned r;
    asm("v_cvt_pk_bf16_f32 %0, %1, %2" : "=v"(r) : "v"(lo), "v"(hi));
    return r;
}

// ---------------------------------------------------------------------------
// Kernel 1: merged PE+LayerNorm (blocks 0..4095) and W transpose+cast
// (blocks 4096..7167). Independent work, block-uniform branch.
// ---------------------------------------------------------------------------
__global__ __launch_bounds__(256) void peln_wt_kernel(
    const float* __restrict__ emb,
    const float* __restrict__ gamma,
    const float* __restrict__ beta,
    const float* __restrict__ Wq,
    const float* __restrict__ Wk,
    const float* __restrict__ Wv,
    __hip_bfloat16* __restrict__ x,
    __hip_bfloat16* __restrict__ Wt)
{
    const int tid = threadIdx.x;
    if (blockIdx.x < 4096) {
        const int row = blockIdx.x;
        const int t   = row & 1023;
        float4 e = ((const float4*)(emb + (size_t)row * 1024))[tid];
        float v[4] = {e.x, e.y, e.z, e.w};
        float s = 0.f, ss = 0.f;
        #pragma unroll
        for (int kk = 0; kk < 4; ++kk) {
            int c = tid * 4 + kk;
            float ang = (float)t * exp2f(-13.287712379549449f * (float)(c >> 1) * (1.0f / 512.0f));
            float pe  = (c & 1) ? __cosf(ang) : __sinf(ang);
            v[kk] += pe;
            s  += v[kk];
            ss += v[kk] * v[kk];
        }
        #pragma unroll
        for (int off = 1; off < 64; off <<= 1) {
            s  += __shfl_xor(s, off);
            ss += __shfl_xor(ss, off);
        }
        __shared__ float red_s[4], red_ss[4];
        int wave = tid >> 6, lane = tid & 63;
        if (lane == 0) { red_s[wave] = s; red_ss[wave] = ss; }
        __syncthreads();
        float S  = red_s[0] + red_s[1] + red_s[2] + red_s[3];
        float SS = red_ss[0] + red_ss[1] + red_ss[2] + red_ss[3];
        float mu   = S * (1.0f / 1024.0f);
        float var  = SS * (1.0f / 1024.0f) - mu * mu;
        float rstd = rsqrtf(var + 1e-5f);
        #pragma unroll
        for (int kk = 0; kk < 4; ++kk) {
            int c = tid * 4 + kk;
            float y = (v[kk] - mu) * rstd * gamma[c] + beta[c];
            x[(size_t)row * 1024 + c] = __float2bfloat16(y);
        }
    } else {
        __shared__ __hip_bfloat16 tile[32][33];
        int wid = blockIdx.x - 4096;         // 0..3071
        int zz  = wid >> 10;
        int rem = wid & 1023;
        int bx = rem & 31, by = rem >> 5;
        int tx = tid & 31, ty = tid >> 5;    // (32,8)
        const float* src = (zz == 0) ? Wq : (zz == 1) ? Wk : Wv;
        __hip_bfloat16* dst = Wt + (size_t)zz * 1024 * 1024;
        int x0 = bx * 32, y0 = by * 32;
        #pragma unroll
        for (int kk = 0; kk < 4; ++kk)
            tile[ty + 8 * kk][tx] =
                __float2bfloat16(src[(size_t)(y0 + ty + 8 * kk) * 1024 + x0 + tx]);
        __syncthreads();
        #pragma unroll
        for (int kk = 0; kk < 4; ++kk)
            dst[(size_t)(x0 + ty + 8 * kk) * 1024 + y0 + tx] = tile[tx][ty + 8 * kk];
    }
}

// ---------------------------------------------------------------------------
// Kernel 2: fused QKV GEMM. m97 loop (measured 29.5 us ~ 874 TF, at the
// structure ceiling). ONLY CHANGE vs round-3: the t==1 (K) and t==2 (V)
// epilogue chunk stores now target MFMA-native subtiled layouts so the attn
// kernel can read fragments fully coalesced straight from global:
//   Kt[bh][key>>5][d>>4][key&31][d&15]   (32x16 subtiles, 1KB each)
//   Vt[bh][d>>5][key>>4][d&31][key&15]   (32x16 subtiles of V^T)
// Same bytes, new addresses; bounce through LDS unchanged.
// ---------------------------------------------------------------------------
__global__ __launch_bounds__(256) void qkv_gemm(
    const __hip_bfloat16* __restrict__ X,    // [4096,1024] bf16
    const __hip_bfloat16* __restrict__ Wt,   // [3][1024][1024] bf16 N-major
    const float* __restrict__ bq,
    const float* __restrict__ bk,
    const float* __restrict__ bv,
    __hip_bfloat16* __restrict__ qkv,        // q flat [4096,1024]; k subtiled
    __hip_bfloat16* __restrict__ vt)         // V^T subtiled [64][2][64][32][16]
{
    union SMem {
        struct { __hip_bfloat16 A[128 * 64]; __hip_bfloat16 B[128 * 64]; } s;
        __hip_bfloat16 C[128 * 132];         // epilogue bounce (pad 132)
    };
    __shared__ __align__(16) SMem sm;

    const int id   = blockIdx.x;             // 0..767
    const int xcd  = id & 7;
    const int rest = id >> 3;                // 0..95
    const int j    = rest % 3;
    const int mblk = rest / 3;               // 0..31
    const int m0   = mblk * 128;
    const int n0   = (xcd * 3 + j) * 128;    // 0..2944
    const int t    = n0 >> 10;
    const int nn0  = n0 & 1023;
    const __hip_bfloat16* W = Wt + (size_t)t * 1024 * 1024;

    const int tid  = threadIdx.x;
    const int wave = tid >> 6, lane = tid & 63;
    const int wm = wave & 1, wn = wave >> 1;
    const int lm = lane & 15, quad = lane >> 4;

    const int srow = lane >> 3;                        // 0..7
    const int skc  = ((lane & 7) ^ srow) * 8;          // element offset
    const int rbase = wave * 32;                       // rows this wave stages
    const __hip_bfloat16* gA = X + (size_t)(m0 + rbase + srow) * 1024 + skc;
    const __hip_bfloat16* gB = W + (size_t)(nn0 + rbase + srow) * 1024 + skc;
    __hip_bfloat16* lA = sm.s.A + rbase * 64;
    __hip_bfloat16* lB = sm.s.B + rbase * 64;

    f32x4 acc[4][4];
    #pragma unroll
    for (int i = 0; i < 4; ++i)
        #pragma unroll
        for (int jj = 0; jj < 4; ++jj)
            acc[i][jj] = (f32x4){0.f, 0.f, 0.f, 0.f};

    // prologue: stage tile 0
    #pragma unroll
    for (int n = 0; n < 4; ++n) {
        gld16(gA + (size_t)n * 8 * 1024, lA + n * 8 * 64);
        gld16(gB + (size_t)n * 8 * 1024, lB + n * 8 * 64);
    }

    for (int k0 = 0; k0 < 1024; k0 += 64) {
        __syncthreads();                     // drains stage(k0) (vmcnt in barrier)

        bf16x8 a[2][4], b[2][4];
        #pragma unroll
        for (int ks = 0; ks < 2; ++ks) {
            #pragma unroll
            for (int i = 0; i < 4; ++i) {
                int row = wm * 64 + i * 16 + lm;
                a[ks][i] = *(const bf16x8*)(sm.s.A + (size_t)row * 64
                                            + (((ks * 4 + quad) ^ (lm & 7)) * 8));
            }
            #pragma unroll
            for (int jj = 0; jj < 4; ++jj) {
                int row = wn * 64 + jj * 16 + lm;
                b[ks][jj] = *(const bf16x8*)(sm.s.B + (size_t)row * 64
                                             + (((ks * 4 + quad) ^ (lm & 7)) * 8));
            }
        }
        __syncthreads();                     // all LDS reads done

        if (k0 + 64 < 1024) {                // stage(k0+64) under MFMA shadow
            #pragma unroll
            for (int n = 0; n < 4; ++n) {
                gld16(gA + (size_t)n * 8 * 1024 + k0 + 64, lA + n * 8 * 64);
                gld16(gB + (size_t)n * 8 * 1024 + k0 + 64, lB + n * 8 * 64);
            }
        }

        #pragma unroll
        for (int ks = 0; ks < 2; ++ks)
            #pragma unroll
            for (int i = 0; i < 4; ++i)
                #pragma unroll
                for (int jj = 0; jj < 4; ++jj)
                    acc[i][jj] = __builtin_amdgcn_mfma_f32_16x16x32_bf16(a[ks][i], b[ks][jj], acc[i][jj], 0, 0, 0);
    }

    const float* bias = (t == 0) ? bq : (t == 1) ? bk : bv;
    if (t < 2) {
        #pragma unroll
        for (int jj = 0; jj < 4; ++jj) {
            int col = wn * 64 + jj * 16 + lm;
            float bb = bias[nn0 + col];
            #pragma unroll
            for (int i = 0; i < 4; ++i)
                #pragma unroll
                for (int r = 0; r < 4; ++r) {
                    int row = wm * 64 + i * 16 + quad * 4 + r;
                    sm.C[(size_t)row * 132 + col] = __float2bfloat16(acc[i][jj][r] + bb);
                }
        }
        __syncthreads();
        if (t == 0) {
            __hip_bfloat16* outq = qkv;
            #pragma unroll
            for (int c = 0; c < 8; ++c) {
                int g = tid + 256 * c;           // 0..2047 chunks of 16B
                int row = g >> 4;
                int colc = (g & 15) * 8;
                bf16x8 vch = *(const bf16x8*)&sm.C[(size_t)row * 132 + colc];
                *(bf16x8*)(outq + (size_t)(m0 + row) * 1024 + nn0 + colc) = vch;
            }
        } else {                                 // K -> subtiled layout
            __hip_bfloat16* kk = qkv + (size_t)4096 * 1024;
            const int b_ = m0 >> 10;             // constant per block
            #pragma unroll
            for (int c = 0; c < 8; ++c) {
                int g = tid + 256 * c;           // 0..2047
                int row = g >> 4;                // 0..127 (local key)
                int colc = (g & 15) * 8;         // 0..120 (local d-col)
                bf16x8 vch = *(const bf16x8*)&sm.C[(size_t)row * 132 + colc];
                int key = (m0 & 1023) + row;
                int gcol = nn0 + colc;
                int bh = b_ * 16 + (gcol >> 6);
                int d = gcol & 63;
                size_t off = ((((size_t)bh * 32 + (key >> 5)) * 4 + (d >> 4)) * 32
                              + (key & 31)) * 16 + (d & 15);
                *(bf16x8*)(kk + off) = vch;
            }
        }
    } else {
        #pragma unroll
        for (int jj = 0; jj < 4; ++jj) {
            int col = wn * 64 + jj * 16 + lm;
            float bb = bias[nn0 + col];
            #pragma unroll
            for (int i = 0; i < 4; ++i)
                #pragma unroll
                for (int r = 0; r < 4; ++r) {
                    int row = wm * 64 + i * 16 + quad * 4 + r;
                    sm.C[(size_t)col * 132 + row] = __float2bfloat16(acc[i][jj][r] + bb);
                }
        }
        __syncthreads();
        const int b_ = m0 >> 10;
        #pragma unroll
        for (int c = 0; c < 8; ++c) {
            int g = tid + 256 * c;               // 0..2047
            int col = g >> 4;                    // 0..127 (local d-col)
            int rch = (g & 15) * 8;              // local key chunk
            bf16x8 vch = *(const bf16x8*)&sm.C[(size_t)col * 132 + rch];
            int dg = nn0 + col;
            int bh = b_ * 16 + (dg >> 6);
            int d = dg & 63;
            int key = (m0 & 1023) + rch;
            size_t off = ((((size_t)bh * 2 + (d >> 5)) * 64 + (key >> 4)) * 32
                          + (d & 31)) * 16 + (key & 15);
            *(bf16x8*)(vt + off) = vch;
        }
    }
}

// ---------------------------------------------------------------------------
// Kernel 3: flash attention v13 — DIRECT-GLOBAL with MFMA-native subtiled
// K/V layouts. v11 proved direct-global is latency-safe but died on the
// 32-line row-gather; the subtiled layouts make every fragment load a fully
// coalesced 1KB wave-load. No LDS, no barriers, no staging — 16 independent
// loads in flight per 64-key sub-round, compiler-counted vmcnt. Softmax/PV
// (32x32x16, in-register P via cvt_pk + permlane32_swap) verbatim from the
// HW-verified v10.
// ---------------------------------------------------------------------------
__global__ __launch_bounds__(256, 2) void attn_kernel(
    const __hip_bfloat16* __restrict__ q,    // [4096,1024] flat
    const __hip_bfloat16* __restrict__ kk,   // subtiled Kt, 64K elems per bh
    const __hip_bfloat16* __restrict__ vt,   // subtiled Vt, 64K elems per bh
    float* __restrict__ out)                 // [4096,1024] f32
{
    const int id   = blockIdx.x;             // 0..511
    const int bh   = (id & 7) * 8 + ((id >> 3) & 7);  // XCD-local K/V
    const int qblk = id >> 6;                // 0..7
    const int b = bh >> 4, h = bh & 15;
    const int wave = threadIdx.x >> 6, lane = threadIdx.x & 63;
    const int l31 = lane & 31, hi5 = lane >> 5;
    const int qbase = qblk * 128 + wave * 32;
    const float CEXP = 0.18033688011112042f; // (1/8) * log2(e)

    // Q fragments: B-operand of 32x32x16, col=q=l31, k(d) = 8*hi5 + e per slab
    bf16x8 bq32[4];
    #pragma unroll
    for (int slab = 0; slab < 4; ++slab)
        bq32[slab] = *(const bf16x8*)(q + (size_t)(b * 1024 + qbase + l31) * 1024
                                        + h * 64 + (slab * 2 + hi5) * 8);

    const __hip_bfloat16* Kt = kk + (size_t)bh * 65536;
    const __hip_bfloat16* Vt = vt + (size_t)bh * 65536;

    f32x16 OT[2];          // O^T accumulators: [dt], col=q, row=d pattern
    #pragma unroll
    for (int dt = 0; dt < 2; ++dt)
        #pragma unroll
        for (int r = 0; r < 16; ++r)
            OT[dt][r] = 0.f;
    float li = 0.f;

    for (int kc = 0; kc < 1024; kc += 64) {
        // ---- QK^T: S^T[64 keys][32 q], 2 key-subtiles x 4 d-slabs ----
        f32x16 ST[2];
        #pragma unroll
        for (int kt = 0; kt < 2; ++kt) {
            #pragma unroll
            for (int r = 0; r < 16; ++r) ST[kt][r] = 0.f;
            #pragma unroll
            for (int slab = 0; slab < 4; ++slab) {
                // Kt[kb= kc/32+kt][ds=slab][km=l31][de=hi5*8..+8] — 1KB coalesced
                bf16x8 ak = *(const bf16x8*)(Kt
                    + ((((size_t)(kc >> 5) + kt) * 4 + slab) * 32 + l31) * 16
                    + hi5 * 8);
                ST[kt] = __builtin_amdgcn_mfma_f32_32x32x16_bf16(ak, bq32[slab], ST[kt], 0, 0, 0);
            }
        }

        // ---- softmax (max-free) + pack P^T into PV B-operand words ----
        unsigned pw[4][4];               // [ks][word]
        #pragma unroll
        for (int kt = 0; kt < 2; ++kt) {
            float pv[16];
            #pragma unroll
            for (int r = 0; r < 16; ++r) {
                pv[r] = __builtin_amdgcn_exp2f(ST[kt][r] * CEXP);
                li += pv[r];
            }
            #pragma unroll
            for (int s = 0; s < 2; ++s) {
                unsigned P0 = cvtpk(pv[8 * s + 0], pv[8 * s + 1]);
                unsigned P1 = cvtpk(pv[8 * s + 2], pv[8 * s + 3]);
                unsigned P2 = cvtpk(pv[8 * s + 4], pv[8 * s + 5]);
                unsigned P3 = cvtpk(pv[8 * s + 6], pv[8 * s + 7]);
                asm("v_permlane32_swap_b32 %0, %1" : "+v"(P0), "+v"(P2));
                asm("v_permlane32_swap_b32 %0, %1" : "+v"(P1), "+v"(P3));
                int ks = kt * 2 + s;
                pw[ks][0] = P0; pw[ks][1] = P1; pw[ks][2] = P2; pw[ks][3] = P3;
            }
        }

        // ---- PV: O^T[64 d][32 q] += V^T · P^T ----
        #pragma unroll
        for (int dt = 0; dt < 2; ++dt)
            #pragma unroll
            for (int ks = 0; ks < 4; ++ks) {
                // Vt[dB=dt][kb16=kc/16+ks][dm=l31][ke=hi5*8..+8] — 1KB coalesced
                bf16x8 av = *(const bf16x8*)(Vt
                    + (((size_t)dt * 64 + (kc >> 4) + ks) * 32 + l31) * 16
                    + hi5 * 8);
                bf16x8 pf;
                __builtin_memcpy(&pf, pw[ks], 16);
                OT[dt] = __builtin_amdgcn_mfma_f32_32x32x16_bf16(av, pf, OT[dt], 0, 0, 0);
            }
    }

    li += __shfl_xor(li, 32);
    float inv = 1.0f / li;
    const int qrow = qbase + l31;

    #pragma unroll
    for (int dt = 0; dt < 2; ++dt)
        #pragma unroll
        for (int g = 0; g < 4; ++g) {
            float4 o4 = {OT[dt][4 * g + 0] * inv, OT[dt][4 * g + 1] * inv,
                         OT[dt][4 * g + 2] * inv, OT[dt][4 * g + 3] * inv};
            *(float4*)(out + (size_t)(b * 1024 + qrow) * 1024
                       + h * 64 + dt * 32 + 8 * g + 4 * hi5) = o4;
        }
}

// ---------------------------------------------------------------------------
extern "C" void kernel_launch(void* const* d_in, const int* in_sizes, int n_in,
                              void* d_out, int out_size, void* d_ws, size_t ws_size,
                              hipStream_t stream)
{
    const float* emb   = (const float*)d_in[0];
    const float* gamma = (const float*)d_in[1];
    const float* beta  = (const float*)d_in[2];
    const float* Wq    = (const float*)d_in[3];
    const float* bq    = (const float*)d_in[4];
    const float* Wk    = (const float*)d_in[5];
    const float* bk    = (const float*)d_in[6];
    const float* Wv    = (const float*)d_in[7];
    const float* bv    = (const float*)d_in[8];
    float* out = (float*)d_out;

    __hip_bfloat16* ws  = (__hip_bfloat16*)d_ws;
    __hip_bfloat16* x   = ws;                            //  4M elems bf16
    __hip_bfloat16* Wt  = x   + (size_t)4096 * 1024;     //  3M elems
    __hip_bfloat16* qkv = Wt  + (size_t)3 * 1024 * 1024; //  8M elems (q flat, k subtiled)
    __hip_bfloat16* vt  = qkv + (size_t)2 * 4096 * 1024; //  4M elems (38MB)

    peln_wt_kernel<<<4096 + 3072, 256, 0, stream>>>(emb, gamma, beta, Wq, Wk, Wv, x, Wt);
    qkv_gemm<<<768, 256, 0, stream>>>(x, Wt, bq, bk, bv, qkv, vt);
    attn_kernel<<<512, 256, 0, stream>>>(qkv, qkv + (size_t)4096 * 1024, vt, out);
}